// Round 1
// baseline (363.018 us; speedup 1.0000x reference)
//
#include <hip/hip_runtime.h>
#include <math.h>

// Problem constants (from reference setup_inputs): x = (16, 32, 65536) fp32.
#define LROW   65536
#define NROWS  512              // 16*32
#define CHUNK  4096
#define NCH    (LROW / CHUNK)   // 16 chunks per row
#define NT     256
#define EPT    (CHUNK / NT)     // 16 elements per thread
#define HALO   5
#define NELEM  (CHUNK + 2 * HALO)

#define TREND_SCALING       0.6f
#define DETAIL_PRESERVATION 0.85f
#define SPIKE_THRESHOLD     3.5f
#define SPIKE_DAMPING       0.35f
#define EPSV                1e-6f

// ws layout (bytes):
//   [0, PART_BYTES)                : double partials[NROWS*NCH*2]
//   [PART_BYTES, PART_BYTES+4096)  : float thr[NROWS]
//   [PART_BYTES+4096, ...)         : float edges[NROWS*NCH*10]
#define PART_BYTES (NROWS * NCH * 2 * 8)

// LDS swizzle: logical stride-16 per-thread fragments would hit 2 banks only
// (32-way conflict). phys = i + i/16 gives per-thread base stride 17 (odd)
// -> all 32 banks covered, 2 lanes/bank (free on gfx950, m136).
__device__ __forceinline__ int sw(int i) { return i + (i >> 4); }

// ---------------------------------------------------------------------------
// k_sum: per-chunk partial sums of residual (r, r^2) in double, deterministic.
// STASH: also stash this chunk's first/last 5 elements into ws for the
// in-place final apply.
// ---------------------------------------------------------------------------
template <bool STASH>
__global__ __launch_bounds__(NT) void k_sum(const float* __restrict__ src,
                                            const float* __restrict__ k5,
                                            double* __restrict__ partials,
                                            float* __restrict__ edges) {
    __shared__ float buf[NELEM + (NELEM >> 4) + 2];
    const int bid = blockIdx.x;
    const int row = bid >> 4;          // NCH == 16
    const int c = bid & (NCH - 1);
    const size_t rowBase = (size_t)row * LROW;
    const int cStart = c * CHUNK;
    const int tid = threadIdx.x;
    const float w5 = k5[0];

    // main chunk: vectorized global read, scalar swizzled LDS writes
    const float4* src4 = (const float4*)(src + rowBase + cStart);
    for (int j4 = tid; j4 < CHUNK / 4; j4 += NT) {
        float4 t4 = src4[j4];
        int l = j4 * 4 + HALO;
        buf[sw(l)] = t4.x;
        buf[sw(l + 1)] = t4.y;
        buf[sw(l + 2)] = t4.z;
        buf[sw(l + 3)] = t4.w;
    }
    // halos from global (src is stable during this kernel), reflect at row ends
    if (tid < 2 * HALO) {
        int j = (tid < HALO) ? tid : (CHUNK + tid);  // 0..4 or CHUNK+5..CHUNK+9
        int g = cStart - HALO + j;
        g = (g < 0) ? -g : (g >= LROW ? 2 * LROW - 2 - g : g);
        buf[sw(j)] = src[rowBase + g];
    }
    __syncthreads();

    if (STASH && tid < 10) {
        int l = (tid < 5) ? (HALO + tid) : (CHUNK + tid - 5);
        edges[(size_t)bid * 10 + tid] = buf[sw(l)];
    }

    float v[EPT + 2 * HALO];
    const int base = tid * EPT;
#pragma unroll
    for (int j = 0; j < EPT + 2 * HALO; j++) v[j] = buf[sw(base + j)];

    double s = 0.0, q = 0.0;
#pragma unroll
    for (int k = 0; k < EPT; k++) {
        float lac = 0.f;
#pragma unroll
        for (int d = 0; d < 5; d++) lac = fmaf(v[k + 3 + d], w5, lac);
        float r = v[k + HALO] - lac;
        s += (double)r;
        q += (double)r * (double)r;
    }

    __shared__ double rs[NT], rq[NT];
    rs[tid] = s;
    rq[tid] = q;
    __syncthreads();
    for (int off = NT / 2; off > 0; off >>= 1) {
        if (tid < off) {
            rs[tid] += rs[tid + off];
            rq[tid] += rq[tid + off];
        }
        __syncthreads();
    }
    if (tid == 0) {
        partials[(size_t)bid * 2] = rs[0];
        partials[(size_t)bid * 2 + 1] = rq[0];
    }
}

// ---------------------------------------------------------------------------
// k_red: finalize per-row threshold = max(std(r, ddof=1), 1e-6) * 3.5
// ---------------------------------------------------------------------------
__global__ void k_red(const double* __restrict__ partials, float* __restrict__ thr) {
    int r = blockIdx.x * blockDim.x + threadIdx.x;
    if (r >= NROWS) return;
    double s = 0.0, q = 0.0;
    for (int c = 0; c < NCH; c++) {
        s += partials[(size_t)(r * NCH + c) * 2];
        q += partials[(size_t)(r * NCH + c) * 2 + 1];
    }
    const double N = (double)LROW;
    double var = (q - s * s / N) / (N - 1.0);
    if (var < 0.0) var = 0.0;
    float sd = (float)sqrt(var);
    float scale = fmaxf(sd, EPSV);
    thr[r] = scale * SPIKE_THRESHOLD;
}

// ---------------------------------------------------------------------------
// k_apply: recompute smooths, damp spikes, recombine, write next "current".
// USE_EDGES: in-place (src==dst) final pass — halos come from ws staging so
// no cross-block race exists. (No __restrict__: src may alias dst.)
// ---------------------------------------------------------------------------
template <bool USE_EDGES>
__global__ __launch_bounds__(NT) void k_apply(const float* src, float* dst,
                                              const float* k5, const float* k11,
                                              const float* thr, const float* edges) {
    __shared__ float buf[NELEM + (NELEM >> 4) + 2];
    const int bid = blockIdx.x;
    const int row = bid >> 4;
    const int c = bid & (NCH - 1);
    const size_t rowBase = (size_t)row * LROW;
    const int cStart = c * CHUNK;
    const int tid = threadIdx.x;
    const float w5 = k5[0];
    const float w11 = k11[0];
    const float th = thr[row];

    const float4* src4 = (const float4*)(src + rowBase + cStart);
    for (int j4 = tid; j4 < CHUNK / 4; j4 += NT) {
        float4 t4 = src4[j4];
        int l = j4 * 4 + HALO;
        buf[sw(l)] = t4.x;
        buf[sw(l + 1)] = t4.y;
        buf[sw(l + 2)] = t4.z;
        buf[sw(l + 3)] = t4.w;
    }
    if (!USE_EDGES) {
        if (tid < 2 * HALO) {
            int j = (tid < HALO) ? tid : (CHUNK + tid);
            int g = cStart - HALO + j;
            g = (g < 0) ? -g : (g >= LROW ? 2 * LROW - 2 - g : g);
            buf[sw(j)] = src[rowBase + g];
        }
        __syncthreads();
    } else {
        __syncthreads();  // own-chunk LDS copy complete before reflect reads
        if (tid < HALO) {
            float val;
            if (c > 0)
                val = edges[((size_t)bid - 1) * 10 + 5 + tid];  // prev chunk's last 5
            else
                val = buf[sw(10 - tid)];  // reflect at row start
            buf[sw(tid)] = val;
        } else if (tid < 2 * HALO) {
            int k = tid - HALO;
            float val;
            if (c < NCH - 1)
                val = edges[((size_t)bid + 1) * 10 + k];  // next chunk's first 5
            else
                val = buf[sw(CHUNK + 3 - k)];  // reflect at row end
            buf[sw(CHUNK + HALO + k)] = val;
        }
        __syncthreads();
    }

    float v[EPT + 2 * HALO];
    const int base = tid * EPT;
#pragma unroll
    for (int j = 0; j < EPT + 2 * HALO; j++) v[j] = buf[sw(base + j)];

    float o[EPT];
#pragma unroll
    for (int k = 0; k < EPT; k++) {
        float lac = 0.f, tac = 0.f;
#pragma unroll
        for (int d = 0; d < 5; d++) lac = fmaf(v[k + 3 + d], w5, lac);
#pragma unroll
        for (int d = 0; d < 11; d++) tac = fmaf(v[k + d], w11, tac);
        float cur = v[k + HALO];
        float r = cur - lac;
        r = (fabsf(r) > th) ? r * SPIKE_DAMPING : r;
        float comb = (1.0f - TREND_SCALING) * lac + TREND_SCALING * tac;
        o[k] = comb + DETAIL_PRESERVATION * r;
    }

    float4* dst4 = (float4*)(dst + rowBase + cStart + base);
#pragma unroll
    for (int k4 = 0; k4 < EPT / 4; k4++) {
        dst4[k4] = make_float4(o[4 * k4], o[4 * k4 + 1], o[4 * k4 + 2], o[4 * k4 + 3]);
    }
}

extern "C" void kernel_launch(void* const* d_in, const int* in_sizes, int n_in,
                              void* d_out, int out_size, void* d_ws, size_t ws_size,
                              hipStream_t stream) {
    const float* x = (const float*)d_in[0];
    const float* k5 = (const float*)d_in[1];
    const float* k11 = (const float*)d_in[2];
    float* out = (float*)d_out;
    char* ws = (char*)d_ws;
    double* partials = (double*)ws;
    float* thr = (float*)(ws + PART_BYTES);
    float* edges = (float*)(ws + PART_BYTES + 4096);

    dim3 grid(NROWS * NCH), block(NT);

    // Iteration 1: current = x, next current -> d_out
    hipLaunchKernelGGL((k_sum<false>), grid, block, 0, stream, x, k5, partials, edges);
    hipLaunchKernelGGL(k_red, dim3(2), dim3(NT), 0, stream, partials, thr);
    hipLaunchKernelGGL((k_apply<false>), grid, block, 0, stream, x, out, k5, k11, thr, edges);

    // Iteration 2: current = d_out, in-place final apply with ws-staged halos
    hipLaunchKernelGGL((k_sum<true>), grid, block, 0, stream, out, k5, partials, edges);
    hipLaunchKernelGGL(k_red, dim3(2), dim3(NT), 0, stream, partials, thr);
    hipLaunchKernelGGL((k_apply<true>), grid, block, 0, stream, out, out, k5, k11, thr, edges);
}